// Round 1
// baseline (1534.229 us; speedup 1.0000x reference)
//
#include <hip/hip_runtime.h>
#include <math.h>

#define TT 4
#define CC 3
#define HH 192
#define WW 192
#define SS 300          // n_spix
#define SP 320          // padded to multiple of SC (pad entries masked -inf)
#define KS 7
#define PD 3
#define TS 16           // output tile
#define HSZ 22          // tile + 2*PD halo
#define NHP (HSZ*HSZ)   // 484
#define SC 32           // superpixel chunk held in LDS
#define HW (HH*WW)

// ---------- ws layout (floats) ----------
// [0, 3600)          sums  [T][S][3]
// [3600, 4800)       cnts  [T][S]
// [4800, 9920)       means float4 [T][SP]  (x,y,z = mean, w = 0 present / -inf absent)

__global__ void k_zero(float* ws) {
    int i = blockIdx.x * 256 + threadIdx.x;
    if (i < TT * SS * 4) ws[i] = 0.f;
}

__global__ void k_accum(const float* __restrict__ x, const int* __restrict__ spix,
                        float* __restrict__ ws) {
    int i = blockIdx.x * 256 + threadIdx.x;
    if (i >= TT * HW) return;
    int t = i / HW, p = i - t * HW;
    int s = spix[i];
    float* sums = ws;
    float* cnts = ws + TT * SS * 3;
    int b = (t * SS + s) * 3;
    atomicAdd(&sums[b + 0], x[(t * 3 + 0) * HW + p]);
    atomicAdd(&sums[b + 1], x[(t * 3 + 1) * HW + p]);
    atomicAdd(&sums[b + 2], x[(t * 3 + 2) * HW + p]);
    atomicAdd(&cnts[t * SS + s], 1.f);
}

__global__ void k_means(float* __restrict__ ws) {
    int i = blockIdx.x * 256 + threadIdx.x;
    if (i >= TT * SP) return;
    int t = i / SP, s = i - t * SP;
    const float* sums = ws;
    const float* cnts = ws + TT * SS * 3;
    float4* m4 = (float4*)(ws + TT * SS * 3 + TT * SS);
    float4 m;
    if (s < SS) {
        float c = cnts[t * SS + s];
        float inv = 1.f / fmaxf(c, 1.f);
        m.x = sums[(t * SS + s) * 3 + 0] * inv;
        m.y = sums[(t * SS + s) * 3 + 1] * inv;
        m.z = sums[(t * SS + s) * 3 + 2] * inv;
        m.w = (c > 0.f) ? 0.f : -INFINITY;
    } else {
        m.x = 0.f; m.y = 0.f; m.z = 0.f; m.w = -INFINITY;
    }
    m4[t * SP + s] = m;
}

// swizzled float index for sims LDS: 16B block jb of row hp lives at block (jb ^ (hp&7))
__device__ __forceinline__ int sim_idx(int hp, int jblk) {
    return hp * SC + ((jblk ^ (hp & 7)) << 2);
}

__launch_bounds__(256, 2)
__global__ void k_main(const float* __restrict__ x, const float* __restrict__ Wlin,
                       const float* __restrict__ blin, const float* __restrict__ ws,
                       float* __restrict__ out) {
    __shared__ float4 smean[SP];
    __shared__ float4 sfh[NHP];              // xyz = feature (0 if OOB), w = c_p (-inf if OOB)
    __shared__ float  sW[CC * CC * KS * KS]; // 441
    __shared__ __align__(16) float ssim[NHP * SC];

    const int tid = threadIdx.x;
    const int tx = tid & 15, ty = tid >> 4;
    const int t = blockIdx.z;
    const int gx0 = blockIdx.x * TS - PD, gy0 = blockIdx.y * TS - PD;

    const float4* m4 = (const float4*)(ws + TT * SS * 3 + TT * SS);
    for (int i = tid; i < SP; i += 256) smean[i] = m4[t * SP + i];
    for (int i = tid; i < CC * CC * KS * KS; i += 256) sW[i] = Wlin[i];
    __syncthreads();

    // ---- halo load + per-pixel softmax stats (phase A) ----
    for (int hp = tid; hp < NHP; hp += 256) {
        int hy = hp / HSZ, hx = hp - hy * HSZ;
        int gy = gy0 + hy, gx = gx0 + hx;
        bool inb = (gy >= 0 && gy < HH && gx >= 0 && gx < WW);
        float fx = 0.f, fy = 0.f, fz = 0.f, cp = -INFINITY;
        if (inb) {
            int p = gy * WW + gx;
            fx = x[(t * 3 + 0) * HW + p];
            fy = x[(t * 3 + 1) * HW + p];
            fz = x[(t * 3 + 2) * HW + p];
            float d2min = INFINITY;
            for (int s = 0; s < SP; s++) {
                float4 m = smean[s];
                float a = fx - m.x, b = fy - m.y, c = fz - m.z;
                float d2 = a * a + b * b + c * c;
                d2min = fminf(d2min, d2 - m.w);   // absent: +inf, excluded
            }
            float Z = 0.f;
            for (int s = 0; s < SP; s++) {
                float4 m = smean[s];
                float a = fx - m.x, b = fy - m.y, c = fz - m.z;
                float d2 = a * a + b * b + c * c;
                Z += __expf(fmaf(-10.f, d2, 10.f * d2min) + m.w);  // absent: exp(-inf)=0
            }
            cp = fmaf(10.f, d2min, -__logf(Z));
        }
        sfh[hp] = make_float4(fx, fy, fz, cp);
    }

    float acc[49];
#pragma unroll
    for (int k = 0; k < 49; k++) acc[k] = 0.f;
    const int own = (ty + PD) * HSZ + (tx + PD);

    for (int cs = 0; cs < SP; cs += SC) {
        __syncthreads();   // previous chunk's MAC reads are done
        // ---- phase B: sims values for this chunk, all halo pixels ----
        for (int hp = tid; hp < NHP; hp += 256) {
            float4 f = sfh[hp];
            int base = hp * SC;
            int sw = (hp & 7) << 2;
#pragma unroll
            for (int j = 0; j < SC; j++) {
                float4 m = smean[cs + j];
                float a = f.x - m.x, b = f.y - m.y, c = f.z - m.z;
                float d2 = a * a + b * b + c * c;
                float e = __expf(fmaf(-10.f, d2, f.w) + m.w);  // 0 for OOB/absent/pad
                ssim[base + ((j & ~3) ^ sw) + (j & 3)] = e;
            }
        }
        __syncthreads();
        // ---- own sims chunk -> registers ----
        float4 own4[8];
        {
            int osw = own & 7;
            int obase = own * SC;
#pragma unroll
            for (int jb = 0; jb < 8; jb++)
                own4[jb] = *(const float4*)&ssim[obase + ((jb ^ osw) << 2)];
        }
        // ---- attn MACs ----
#pragma unroll
        for (int k = 0; k < 49; k++) {
            int q = own + ((k / 7) - PD) * HSZ + ((k % 7) - PD);
            int qb = q * SC;
            int qsw = q & 7;
            float a = acc[k];
#pragma unroll
            for (int jb = 0; jb < 8; jb++) {
                float4 n = *(const float4*)&ssim[qb + ((jb ^ qsw) << 2)];
                a += own4[jb].x * n.x;
                a += own4[jb].y * n.y;
                a += own4[jb].z * n.z;
                a += own4[jb].w * n.w;
            }
            acc[k] = a;
        }
    }

    // ---- max-normalize + linear epilogue ----
    float mx = 0.f;
#pragma unroll
    for (int k = 0; k < 49; k++) mx = fmaxf(mx, acc[k]);
    float inv = 1.f / (1e-5f + mx);

    float o0 = blin[0], o1 = blin[1], o2 = blin[2];
#pragma unroll
    for (int k = 0; k < 49; k++) {
        float rwk = acc[k] * inv;
        int q = own + ((k / 7) - PD) * HSZ + ((k % 7) - PD);
        float4 f = sfh[q];
        o0 += rwk * (sW[0 * 147 + k] * f.x + sW[0 * 147 + 49 + k] * f.y + sW[0 * 147 + 98 + k] * f.z);
        o1 += rwk * (sW[1 * 147 + k] * f.x + sW[1 * 147 + 49 + k] * f.y + sW[1 * 147 + 98 + k] * f.z);
        o2 += rwk * (sW[2 * 147 + k] * f.x + sW[2 * 147 + 49 + k] * f.y + sW[2 * 147 + 98 + k] * f.z);
    }
    int gy = gy0 + PD + ty, gx = gx0 + PD + tx;
    int p = gy * WW + gx;
    out[(t * 3 + 0) * HW + p] = o0;
    out[(t * 3 + 1) * HW + p] = o1;
    out[(t * 3 + 2) * HW + p] = o2;
}

extern "C" void kernel_launch(void* const* d_in, const int* in_sizes, int n_in,
                              void* d_out, int out_size, void* d_ws, size_t ws_size,
                              hipStream_t stream) {
    const float* x    = (const float*)d_in[0];
    const int*   spix = (const int*)d_in[1];
    const float* Wlin = (const float*)d_in[2];
    const float* blin = (const float*)d_in[3];
    float* out = (float*)d_out;
    float* ws  = (float*)d_ws;

    hipLaunchKernelGGL(k_zero,  dim3((TT * SS * 4 + 255) / 256), dim3(256), 0, stream, ws);
    hipLaunchKernelGGL(k_accum, dim3((TT * HW + 255) / 256),     dim3(256), 0, stream, x, spix, ws);
    hipLaunchKernelGGL(k_means, dim3((TT * SP + 255) / 256),     dim3(256), 0, stream, ws);
    hipLaunchKernelGGL(k_main,  dim3(WW / TS, HH / TS, TT),      dim3(256), 0, stream,
                       x, Wlin, blin, ws, out);
}

// Round 2
// 414.288 us; speedup vs baseline: 3.7033x; 3.7033x over previous
//
#include <hip/hip_runtime.h>
#include <math.h>

#define TT 4
#define CC 3
#define HH 192
#define WW 192
#define SS 300          // n_spix
#define SP 320          // padded to multiple of SC (pad entries masked -inf)
#define KS 7
#define PD 3
#define TS 16           // output tile
#define HSZ 22          // tile + 2*PD halo
#define NHP (HSZ*HSZ)   // 484
#define SC 32           // superpixel chunk held in LDS
#define SROW 40         // padded fp16 row stride (80B): 20 words mod 32 banks -> uniform spread
#define HW (HH*WW)

typedef _Float16 h2 __attribute__((ext_vector_type(2)));

union U16 {                 // one 16B LDS beat = 8 halves = 4 half2
    unsigned int w[4];
    h2 h[4];
};

// ---------- ws layout (floats) ----------
// [0, 3600)          sums  [T][S][3]
// [3600, 4800)       cnts  [T][S]
// [4800, 9920)       means float4 [T][SP]  (x,y,z = mean, w = 0 present / -inf absent)

__global__ void k_zero(float* ws) {
    int i = blockIdx.x * 256 + threadIdx.x;
    if (i < TT * SS * 4) ws[i] = 0.f;
}

__global__ void k_accum(const float* __restrict__ x, const int* __restrict__ spix,
                        float* __restrict__ ws) {
    int i = blockIdx.x * 256 + threadIdx.x;
    if (i >= TT * HW) return;
    int t = i / HW, p = i - t * HW;
    int s = spix[i];
    float* sums = ws;
    float* cnts = ws + TT * SS * 3;
    int b = (t * SS + s) * 3;
    atomicAdd(&sums[b + 0], x[(t * 3 + 0) * HW + p]);
    atomicAdd(&sums[b + 1], x[(t * 3 + 1) * HW + p]);
    atomicAdd(&sums[b + 2], x[(t * 3 + 2) * HW + p]);
    atomicAdd(&cnts[t * SS + s], 1.f);
}

__global__ void k_means(float* __restrict__ ws) {
    int i = blockIdx.x * 256 + threadIdx.x;
    if (i >= TT * SP) return;
    int t = i / SP, s = i - t * SP;
    const float* sums = ws;
    const float* cnts = ws + TT * SS * 3;
    float4* m4 = (float4*)(ws + TT * SS * 3 + TT * SS);
    float4 m;
    if (s < SS) {
        float c = cnts[t * SS + s];
        float inv = 1.f / fmaxf(c, 1.f);
        m.x = sums[(t * SS + s) * 3 + 0] * inv;
        m.y = sums[(t * SS + s) * 3 + 1] * inv;
        m.z = sums[(t * SS + s) * 3 + 2] * inv;
        m.w = (c > 0.f) ? 0.f : -INFINITY;
    } else {
        m.x = 0.f; m.y = 0.f; m.z = 0.f; m.w = -INFINITY;
    }
    m4[t * SP + s] = m;
}

// repeat macro over the 49 window offsets (literal k -> all acc[] indices static)
#define REP49(M) M(0)M(1)M(2)M(3)M(4)M(5)M(6)M(7)M(8)M(9)M(10)M(11)M(12)M(13) \
    M(14)M(15)M(16)M(17)M(18)M(19)M(20)M(21)M(22)M(23)M(24)M(25)M(26)M(27) \
    M(28)M(29)M(30)M(31)M(32)M(33)M(34)M(35)M(36)M(37)M(38)M(39)M(40)M(41) \
    M(42)M(43)M(44)M(45)M(46)M(47)M(48)

#define QOFF(k) (((k) / 7 - PD) * HSZ + ((k) % 7 - PD))

__launch_bounds__(256, 3)
__global__ void k_main(const float* __restrict__ x, const float* __restrict__ Wlin,
                       const float* __restrict__ blin, const float* __restrict__ ws,
                       float* __restrict__ out) {
    __shared__ float4 smean[SP];
    __shared__ float4 sfh[NHP];              // xyz = feature (0 if OOB), w = c_p (-inf if OOB)
    __shared__ float  sW[CC * CC * KS * KS]; // 441
    __shared__ __align__(16) _Float16 ssim[NHP * SROW];

    const int tid = threadIdx.x;
    const int tx = tid & 15, ty = tid >> 4;
    const int t = blockIdx.z;
    const int gx0 = blockIdx.x * TS - PD, gy0 = blockIdx.y * TS - PD;

    const float4* m4 = (const float4*)(ws + TT * SS * 3 + TT * SS);
    for (int i = tid; i < SP; i += 256) smean[i] = m4[t * SP + i];
    for (int i = tid; i < CC * CC * KS * KS; i += 256) sW[i] = Wlin[i];
    __syncthreads();

    // ---- phase A: halo load + per-pixel softmax constant c_p ----
    for (int hp = tid; hp < NHP; hp += 256) {
        int hy = hp / HSZ, hx = hp - hy * HSZ;
        int gy = gy0 + hy, gx = gx0 + hx;
        bool inb = (gy >= 0 && gy < HH && gx >= 0 && gx < WW);
        float fx = 0.f, fy = 0.f, fz = 0.f, cp = -INFINITY;
        if (inb) {
            int p = gy * WW + gx;
            fx = x[(t * 3 + 0) * HW + p];
            fy = x[(t * 3 + 1) * HW + p];
            fz = x[(t * 3 + 2) * HW + p];
            float d2min = INFINITY;
            for (int s = 0; s < SP; s++) {
                float4 m = smean[s];
                float a = fx - m.x, b = fy - m.y, c = fz - m.z;
                float d2 = a * a + b * b + c * c;
                d2min = fminf(d2min, d2 - m.w);   // absent: +inf, excluded
            }
            float Z = 0.f;
            for (int s = 0; s < SP; s++) {
                float4 m = smean[s];
                float a = fx - m.x, b = fy - m.y, c = fz - m.z;
                float d2 = a * a + b * b + c * c;
                Z += __expf(fmaf(-10.f, d2, 10.f * d2min) + m.w);  // absent: exp(-inf)=0
            }
            cp = fmaf(10.f, d2min, -__logf(Z));
        }
        sfh[hp] = make_float4(fx, fy, fz, cp);
    }

    float acc[49];
#define ZK(k) acc[k] = 0.f;
    REP49(ZK)
#undef ZK
    const int own = (ty + PD) * HSZ + (tx + PD);

    for (int cs = 0; cs < SP; cs += SC) {
        __syncthreads();   // previous chunk's MAC reads are done
        // ---- phase B: fp16 sims for this chunk, all halo pixels ----
        for (int hp = tid; hp < NHP; hp += 256) {
            float4 f = sfh[hp];
            _Float16* row = &ssim[hp * SROW];
#pragma unroll
            for (int j = 0; j < SC; j += 2) {
                float4 m0 = smean[cs + j];
                float4 m1 = smean[cs + j + 1];
                float a0 = f.x - m0.x, b0 = f.y - m0.y, c0 = f.z - m0.z;
                float a1 = f.x - m1.x, b1 = f.y - m1.y, c1 = f.z - m1.z;
                float d20 = a0 * a0 + b0 * b0 + c0 * c0;
                float d21 = a1 * a1 + b1 * b1 + c1 * c1;
                float e0 = __expf(fmaf(-10.f, d20, f.w) + m0.w);  // 0 for OOB/absent/pad
                float e1 = __expf(fmaf(-10.f, d21, f.w) + m1.w);
                h2 v;
                v.x = (_Float16)e0;
                v.y = (_Float16)e1;
                *(h2*)&row[j] = v;
            }
        }
        __syncthreads();
        // ---- own sims chunk -> registers (16 half2) ----
        const U16* orow = (const U16*)&ssim[(unsigned)own * SROW];
        U16 ow0 = orow[0], ow1 = orow[1], ow2 = orow[2], ow3 = orow[3];
        h2 o[16];
        o[0] = ow0.h[0];  o[1] = ow0.h[1];  o[2] = ow0.h[2];  o[3] = ow0.h[3];
        o[4] = ow1.h[0];  o[5] = ow1.h[1];  o[6] = ow1.h[2];  o[7] = ow1.h[3];
        o[8] = ow2.h[0];  o[9] = ow2.h[1];  o[10] = ow2.h[2]; o[11] = ow2.h[3];
        o[12] = ow3.h[0]; o[13] = ow3.h[1]; o[14] = ow3.h[2]; o[15] = ow3.h[3];
        // ---- attn MACs: 49 offsets x 4 ds_read_b128 x 16 v_dot2_f32_f16 ----
#define MACK(k) { \
        const U16* nr = (const U16*)&ssim[(unsigned)(own + QOFF(k)) * SROW]; \
        U16 q0 = nr[0], q1 = nr[1], q2 = nr[2], q3 = nr[3]; \
        float aA = acc[k], aB = 0.f; \
        aA = __builtin_amdgcn_fdot2(o[0],  q0.h[0], aA, false); \
        aB = __builtin_amdgcn_fdot2(o[1],  q0.h[1], aB, false); \
        aA = __builtin_amdgcn_fdot2(o[2],  q0.h[2], aA, false); \
        aB = __builtin_amdgcn_fdot2(o[3],  q0.h[3], aB, false); \
        aA = __builtin_amdgcn_fdot2(o[4],  q1.h[0], aA, false); \
        aB = __builtin_amdgcn_fdot2(o[5],  q1.h[1], aB, false); \
        aA = __builtin_amdgcn_fdot2(o[6],  q1.h[2], aA, false); \
        aB = __builtin_amdgcn_fdot2(o[7],  q1.h[3], aB, false); \
        aA = __builtin_amdgcn_fdot2(o[8],  q2.h[0], aA, false); \
        aB = __builtin_amdgcn_fdot2(o[9],  q2.h[1], aB, false); \
        aA = __builtin_amdgcn_fdot2(o[10], q2.h[2], aA, false); \
        aB = __builtin_amdgcn_fdot2(o[11], q2.h[3], aB, false); \
        aA = __builtin_amdgcn_fdot2(o[12], q3.h[0], aA, false); \
        aB = __builtin_amdgcn_fdot2(o[13], q3.h[1], aB, false); \
        aA = __builtin_amdgcn_fdot2(o[14], q3.h[2], aA, false); \
        aB = __builtin_amdgcn_fdot2(o[15], q3.h[3], aB, false); \
        acc[k] = aA + aB; }
        REP49(MACK)
#undef MACK
    }

    // ---- max-normalize + linear epilogue ----
    float mx = 0.f;
#define MXK(k) mx = fmaxf(mx, acc[k]);
    REP49(MXK)
#undef MXK
    float inv = 1.f / (1e-5f + mx);

    float o0 = blin[0], o1 = blin[1], o2 = blin[2];
#define EPIK(k) { \
        float rwk = acc[k] * inv; \
        float4 f = sfh[own + QOFF(k)]; \
        o0 += rwk * (sW[0 * 147 + (k)] * f.x + sW[0 * 147 + 49 + (k)] * f.y + sW[0 * 147 + 98 + (k)] * f.z); \
        o1 += rwk * (sW[1 * 147 + (k)] * f.x + sW[1 * 147 + 49 + (k)] * f.y + sW[1 * 147 + 98 + (k)] * f.z); \
        o2 += rwk * (sW[2 * 147 + (k)] * f.x + sW[2 * 147 + 49 + (k)] * f.y + sW[2 * 147 + 98 + (k)] * f.z); }
    REP49(EPIK)
#undef EPIK

    int gy = gy0 + PD + ty, gx = gx0 + PD + tx;
    int p = gy * WW + gx;
    out[(t * 3 + 0) * HW + p] = o0;
    out[(t * 3 + 1) * HW + p] = o1;
    out[(t * 3 + 2) * HW + p] = o2;
}

extern "C" void kernel_launch(void* const* d_in, const int* in_sizes, int n_in,
                              void* d_out, int out_size, void* d_ws, size_t ws_size,
                              hipStream_t stream) {
    const float* x    = (const float*)d_in[0];
    const int*   spix = (const int*)d_in[1];
    const float* Wlin = (const float*)d_in[2];
    const float* blin = (const float*)d_in[3];
    float* out = (float*)d_out;
    float* ws  = (float*)d_ws;

    hipLaunchKernelGGL(k_zero,  dim3((TT * SS * 4 + 255) / 256), dim3(256), 0, stream, ws);
    hipLaunchKernelGGL(k_accum, dim3((TT * HW + 255) / 256),     dim3(256), 0, stream, x, spix, ws);
    hipLaunchKernelGGL(k_means, dim3((TT * SP + 255) / 256),     dim3(256), 0, stream, ws);
    hipLaunchKernelGGL(k_main,  dim3(WW / TS, HH / TS, TT),      dim3(256), 0, stream,
                       x, Wlin, blin, ws, out);
}

// Round 3
// 285.240 us; speedup vs baseline: 5.3787x; 1.4524x over previous
//
#include <hip/hip_runtime.h>
#include <math.h>

#define TT 4
#define CC 3
#define HH 192
#define WW 192
#define SS 300          // n_spix
#define SP 320          // padded to multiple of SC (pad entries masked -inf)
#define KS 7
#define PD 3
#define TS 16           // output tile
#define HSZ 22          // tile + 2*PD halo
#define NHP (HSZ*HSZ)   // 484
#define SC 32           // superpixel chunk held in LDS
#define SROW 40         // fp16 row stride (80 B = 20 words): 8 consecutive rows cover all 32 banks
#define HW (HH*WW)

typedef _Float16 h2 __attribute__((ext_vector_type(2)));
typedef _Float16 h8 __attribute__((ext_vector_type(8)));

// ---------- ws layout (floats) ----------
// [0, 3600)          sums  [T][S][3]
// [3600, 4800)       cnts  [T][S]
// [4800, 9920)       means float4 [T][SP]  (x,y,z = mean, w = 0 present / -inf absent)

__global__ void k_zero(float* ws) {
    int i = blockIdx.x * 256 + threadIdx.x;
    if (i < TT * SS * 4) ws[i] = 0.f;
}

__global__ void k_accum(const float* __restrict__ x, const int* __restrict__ spix,
                        float* __restrict__ ws) {
    int i = blockIdx.x * 256 + threadIdx.x;
    if (i >= TT * HW) return;
    int t = i / HW, p = i - t * HW;
    int s = spix[i];
    float* sums = ws;
    float* cnts = ws + TT * SS * 3;
    int b = (t * SS + s) * 3;
    atomicAdd(&sums[b + 0], x[(t * 3 + 0) * HW + p]);
    atomicAdd(&sums[b + 1], x[(t * 3 + 1) * HW + p]);
    atomicAdd(&sums[b + 2], x[(t * 3 + 2) * HW + p]);
    atomicAdd(&cnts[t * SS + s], 1.f);
}

__global__ void k_means(float* __restrict__ ws) {
    int i = blockIdx.x * 256 + threadIdx.x;
    if (i >= TT * SP) return;
    int t = i / SP, s = i - t * SP;
    const float* sums = ws;
    const float* cnts = ws + TT * SS * 3;
    float4* m4 = (float4*)(ws + TT * SS * 3 + TT * SS);
    float4 m;
    if (s < SS) {
        float c = cnts[t * SS + s];
        float inv = 1.f / fmaxf(c, 1.f);
        m.x = sums[(t * SS + s) * 3 + 0] * inv;
        m.y = sums[(t * SS + s) * 3 + 1] * inv;
        m.z = sums[(t * SS + s) * 3 + 2] * inv;
        m.w = (c > 0.f) ? 0.f : -INFINITY;
    } else {
        m.x = 0.f; m.y = 0.f; m.z = 0.f; m.w = -INFINITY;
    }
    m4[t * SP + s] = m;
}

#define REP49(M) M(0)M(1)M(2)M(3)M(4)M(5)M(6)M(7)M(8)M(9)M(10)M(11)M(12)M(13) \
    M(14)M(15)M(16)M(17)M(18)M(19)M(20)M(21)M(22)M(23)M(24)M(25)M(26)M(27) \
    M(28)M(29)M(30)M(31)M(32)M(33)M(34)M(35)M(36)M(37)M(38)M(39)M(40)M(41) \
    M(42)M(43)M(44)M(45)M(46)M(47)M(48)

#define QOFF(k) (((k) / 7 - PD) * HSZ + ((k) % 7 - PD))

// one v_dot2_f32_f16: a += A[2i:2i+1] . B[2i:2i+1]
#define D2(a, A, B, i) a = __builtin_amdgcn_fdot2( \
        __builtin_shufflevector(A, A, 2*(i), 2*(i)+1), \
        __builtin_shufflevector(B, B, 2*(i), 2*(i)+1), a, false);

__launch_bounds__(256, 3)
__global__ void k_main(const float* __restrict__ x, const float* __restrict__ Wlin,
                       const float* __restrict__ blin, const float* __restrict__ ws,
                       float* __restrict__ out) {
    __shared__ float4 sfh[NHP];              // xyz = feature (0 if OOB), w = c_p (-inf if OOB)
    __shared__ float  sW[CC * CC * KS * KS]; // 441
    __shared__ __align__(16) _Float16 ssim[NHP * SROW];

    const int tid = threadIdx.x;
    const int tx = tid & 15, ty = tid >> 4;
    const int t = blockIdx.z;
    const int gx0 = blockIdx.x * TS - PD, gy0 = blockIdx.y * TS - PD;

    // means table: uniform-index global reads (K$ / scalar path, off the LDS pipe)
    const float4* m4 = (const float4*)(ws + TT * SS * 3 + TT * SS) + t * SP;

    for (int i = tid; i < CC * CC * KS * KS; i += 256) sW[i] = Wlin[i];

    // ---- phase A: halo load + per-pixel softmax constant c_p ----
    for (int hp = tid; hp < NHP; hp += 256) {
        int hy = hp / HSZ, hx = hp - hy * HSZ;
        int gy = gy0 + hy, gx = gx0 + hx;
        bool inb = (gy >= 0 && gy < HH && gx >= 0 && gx < WW);
        float fx = 0.f, fy = 0.f, fz = 0.f, cp = -INFINITY;
        if (inb) {
            int p = gy * WW + gx;
            fx = x[(t * 3 + 0) * HW + p];
            fy = x[(t * 3 + 1) * HW + p];
            fz = x[(t * 3 + 2) * HW + p];
            float d2min = INFINITY;
#pragma unroll 4
            for (int s = 0; s < SP; s++) {
                float4 m = m4[s];
                float a = fx - m.x, b = fy - m.y, c = fz - m.z;
                float d2 = a * a + b * b + c * c;
                d2min = fminf(d2min, d2 - m.w);   // absent: +inf, excluded
            }
            float Z = 0.f;
#pragma unroll 4
            for (int s = 0; s < SP; s++) {
                float4 m = m4[s];
                float a = fx - m.x, b = fy - m.y, c = fz - m.z;
                float d2 = a * a + b * b + c * c;
                Z += __expf(fmaf(-10.f, d2, 10.f * d2min) + m.w);  // absent: exp(-inf)=0
            }
            cp = fmaf(10.f, d2min, -__logf(Z));
        }
        sfh[hp] = make_float4(fx, fy, fz, cp);
    }

#define ZK(k) float acc##k = 0.f;
    REP49(ZK)
#undef ZK
    const int own = (ty + PD) * HSZ + (tx + PD);

#pragma unroll 1
    for (int cs = 0; cs < SP; cs += SC) {
        __syncthreads();   // previous chunk's MAC reads done; phase A visible on first pass
        // ---- phase B: fp16 sims for this chunk, all halo pixels, b128 stores ----
        for (int hp = tid; hp < NHP; hp += 256) {
            float4 f = sfh[hp];
            h8* row = (h8*)&ssim[hp * SROW];
#pragma unroll
            for (int jb = 0; jb < 4; jb++) {
                h8 v;
#pragma unroll
                for (int j = 0; j < 8; j++) {
                    float4 m = m4[cs + jb * 8 + j];
                    float a = f.x - m.x, b = f.y - m.y, c = f.z - m.z;
                    float d2 = a * a + b * b + c * c;
                    v[j] = (_Float16)__expf(fmaf(-10.f, d2, f.w) + m.w); // 0 for OOB/absent/pad
                }
                row[jb] = v;
            }
        }
        __syncthreads();
        // ---- own sims chunk -> 4 h8 registers ----
        const h8* orow = (const h8*)&ssim[(unsigned)own * SROW];
        h8 ow0 = orow[0], ow1 = orow[1], ow2 = orow[2], ow3 = orow[3];
        // ---- attn MACs: 49 offsets x 4 ds_read_b128 x 16 v_dot2_f32_f16 ----
#define MACK(k) { \
        const h8* nr = (const h8*)&ssim[(unsigned)(own + QOFF(k)) * SROW]; \
        h8 q0 = nr[0], q1 = nr[1], q2 = nr[2], q3 = nr[3]; \
        float aA = acc##k, aB = 0.f; \
        D2(aA, ow0, q0, 0) D2(aB, ow0, q0, 1) D2(aA, ow0, q0, 2) D2(aB, ow0, q0, 3) \
        D2(aA, ow1, q1, 0) D2(aB, ow1, q1, 1) D2(aA, ow1, q1, 2) D2(aB, ow1, q1, 3) \
        D2(aA, ow2, q2, 0) D2(aB, ow2, q2, 1) D2(aA, ow2, q2, 2) D2(aB, ow2, q2, 3) \
        D2(aA, ow3, q3, 0) D2(aB, ow3, q3, 1) D2(aA, ow3, q3, 2) D2(aB, ow3, q3, 3) \
        acc##k = aA + aB; }
        REP49(MACK)
#undef MACK
    }

    // ---- max-normalize + linear epilogue ----
    float mx = 0.f;
#define MXK(k) mx = fmaxf(mx, acc##k);
    REP49(MXK)
#undef MXK
    float inv = 1.f / (1e-5f + mx);

    float o0 = blin[0], o1 = blin[1], o2 = blin[2];
#define EPIK(k) { \
        float rwk = acc##k * inv; \
        float4 f = sfh[own + QOFF(k)]; \
        o0 += rwk * (sW[0 * 147 + (k)] * f.x + sW[0 * 147 + 49 + (k)] * f.y + sW[0 * 147 + 98 + (k)] * f.z); \
        o1 += rwk * (sW[1 * 147 + (k)] * f.x + sW[1 * 147 + 49 + (k)] * f.y + sW[1 * 147 + 98 + (k)] * f.z); \
        o2 += rwk * (sW[2 * 147 + (k)] * f.x + sW[2 * 147 + 49 + (k)] * f.y + sW[2 * 147 + 98 + (k)] * f.z); }
    REP49(EPIK)
#undef EPIK

    int gy = gy0 + PD + ty, gx = gx0 + PD + tx;
    int p = gy * WW + gx;
    out[(t * 3 + 0) * HW + p] = o0;
    out[(t * 3 + 1) * HW + p] = o1;
    out[(t * 3 + 2) * HW + p] = o2;
}

extern "C" void kernel_launch(void* const* d_in, const int* in_sizes, int n_in,
                              void* d_out, int out_size, void* d_ws, size_t ws_size,
                              hipStream_t stream) {
    const float* x    = (const float*)d_in[0];
    const int*   spix = (const int*)d_in[1];
    const float* Wlin = (const float*)d_in[2];
    const float* blin = (const float*)d_in[3];
    float* out = (float*)d_out;
    float* ws  = (float*)d_ws;

    hipLaunchKernelGGL(k_zero,  dim3((TT * SS * 4 + 255) / 256), dim3(256), 0, stream, ws);
    hipLaunchKernelGGL(k_accum, dim3((TT * HW + 255) / 256),     dim3(256), 0, stream, x, spix, ws);
    hipLaunchKernelGGL(k_means, dim3((TT * SP + 255) / 256),     dim3(256), 0, stream, ws);
    hipLaunchKernelGGL(k_main,  dim3(WW / TS, HH / TS, TT),      dim3(256), 0, stream,
                       x, Wlin, blin, ws, out);
}